// Round 1
// baseline (287.855 us; speedup 1.0000x reference)
//
#include <hip/hip_runtime.h>

#define ALPHA 0.2f

typedef __attribute__((ext_vector_type(8))) short short8;
typedef __attribute__((ext_vector_type(4))) float f32x4;

__device__ __forceinline__ short f2bf(float f) {
    unsigned u = __builtin_bit_cast(unsigned, f);
    u += 0x7fffu + ((u >> 16) & 1u);   // round-to-nearest-even
    return (short)(u >> 16);
}

__device__ __forceinline__ float lrelu(float v) { return v > 0.f ? v : ALPHA * v; }

// ---- weight prep: f32 [K][N] row-major -> bf16 transposed [N][Kpad] ----
__global__ void prep_kernel(const float* __restrict__ feW0, const float* __restrict__ feW1,
                            const float* __restrict__ feW2, const float* __restrict__ fnW0,
                            const float* __restrict__ fnW1,
                            short* __restrict__ W0T, short* __restrict__ W1T,
                            short* __restrict__ W2T, short* __restrict__ Wn0T,
                            short* __restrict__ Wn1T)
{
    const int tid = blockIdx.x * blockDim.x + threadIdx.x;
    const int T = gridDim.x * blockDim.x;
    // W0T: [256][160] from feW0 [129][256]; k=128 is the dist row, k>=129 zero-pad
    for (int t = tid; t < 256 * 160; t += T) { int n = t / 160, k = t - n * 160; W0T[t] = f2bf(k < 129 ? feW0[k * 256 + n] : 0.f); }
    // W1T: [256][256] from feW1 [256][256]
    for (int t = tid; t < 256 * 256; t += T) { int n = t >> 8, k = t & 255; W1T[t] = f2bf(feW1[k * 256 + n]); }
    // W2T: [128][256] from feW2 [256][96]; n>=96 zero-pad
    for (int t = tid; t < 128 * 256; t += T) { int n = t >> 8, k = t & 255; W2T[t] = f2bf(n < 96 ? feW2[k * 96 + n] : 0.f); }
    // Wn0T: [256][160] from fnW0 [160][256]
    for (int t = tid; t < 256 * 160; t += T) { int n = t / 160, k = t - n * 160; Wn0T[t] = f2bf(fnW0[k * 256 + n]); }
    // Wn1T: [64][256] from fnW1 [256][64]
    for (int t = tid; t < 64 * 256; t += T) { int n = t >> 8, k = t & 255; Wn1T[t] = f2bf(fnW1[k * 64 + n]); }
}

// ---- edge MLP + aggregation: one block per (b,i); M=64 rows (j) ----
// LDS ping-pong: P holds A[64][168] then h1[64][264]; Q holds xs(f32 64x64) then h0[64][264].
__global__ __launch_bounds__(256, 2)
void edge_kernel(const float* __restrict__ x,
                 const short* __restrict__ W0T, const short* __restrict__ W1T,
                 const short* __restrict__ W2T,
                 const float* __restrict__ b0, const float* __restrict__ b1,
                 const float* __restrict__ b2,
                 float* __restrict__ agg)
{
    __shared__ short P[64 * 264];
    __shared__ short Q[64 * 264];
    const int tid = threadIdx.x;
    const int lane = tid & 63, wid = tid >> 6;
    const int l15 = lane & 15, lg = lane >> 4;
    const int bid = blockIdx.x;
    const int b = bid >> 6, i = bid & 63;

    // stage x[b,:,:] (f32) into Q
    float* xs = reinterpret_cast<float*>(Q);
    const float* xb = x + b * 4096;
    for (int t = tid; t < 4096; t += 256) xs[t] = xb[t];
    __syncthreads();

    // build A[j][0:64]=x[b,i], [64:128]=x[b,j], [128]=dist, [129:168]=0  (bf16, stride 168)
    {
        const int j = tid >> 2, part = tid & 3;
        const int f0 = part * 16;
        float ss = 0.f;
        #pragma unroll
        for (int f = 0; f < 16; ++f) {
            float d = xs[j * 64 + f0 + f] - xs[i * 64 + f0 + f] + 1e-12f;
            ss += d * d;
        }
        ss += __shfl_xor(ss, 1);
        ss += __shfl_xor(ss, 2);
        float dist = sqrtf(ss);
        #pragma unroll
        for (int f = 0; f < 16; ++f) {
            P[j * 168 + f0 + f]      = f2bf(xs[i * 64 + f0 + f]);
            P[j * 168 + 64 + f0 + f] = f2bf(xs[j * 64 + f0 + f]);
        }
        if (part == 0) {
            P[j * 168 + 128] = f2bf(dist);
            for (int c = 129; c < 168; ++c) P[j * 168 + c] = 0;
        }
    }
    __syncthreads();

    // ---- layer 0: h0 = lrelu(A @ W0 + b0), K=160 (5 ksteps), N=256 (64 cols/wave) ----
    {
        f32x4 acc[4][4];
        #pragma unroll
        for (int mt = 0; mt < 4; ++mt)
            #pragma unroll
            for (int nt = 0; nt < 4; ++nt) acc[mt][nt] = (f32x4){0.f, 0.f, 0.f, 0.f};
        const int n0 = wid * 64;
        #pragma unroll
        for (int ks = 0; ks < 5; ++ks) {
            const int k0 = ks * 32 + lg * 8;
            short8 a[4], bf[4];
            #pragma unroll
            for (int mt = 0; mt < 4; ++mt)
                a[mt] = *reinterpret_cast<const short8*>(&P[(mt * 16 + l15) * 168 + k0]);
            #pragma unroll
            for (int nt = 0; nt < 4; ++nt)
                bf[nt] = *reinterpret_cast<const short8*>(&W0T[(n0 + nt * 16 + l15) * 160 + k0]);
            #pragma unroll
            for (int mt = 0; mt < 4; ++mt)
                #pragma unroll
                for (int nt = 0; nt < 4; ++nt)
                    acc[mt][nt] = __builtin_amdgcn_mfma_f32_16x16x32_bf16(a[mt], bf[nt], acc[mt][nt], 0, 0, 0);
        }
        #pragma unroll
        for (int nt = 0; nt < 4; ++nt) {
            const int col = n0 + nt * 16 + l15;
            const float bv = b0[col];
            #pragma unroll
            for (int mt = 0; mt < 4; ++mt)
                #pragma unroll
                for (int r = 0; r < 4; ++r)
                    Q[(mt * 16 + lg * 4 + r) * 264 + col] = f2bf(lrelu(acc[mt][nt][r] + bv));
        }
    }
    __syncthreads();

    // ---- layer 1: h1 = lrelu(h0 @ W1 + b1), K=256 (8 ksteps), N=256 ----
    {
        f32x4 acc[4][4];
        #pragma unroll
        for (int mt = 0; mt < 4; ++mt)
            #pragma unroll
            for (int nt = 0; nt < 4; ++nt) acc[mt][nt] = (f32x4){0.f, 0.f, 0.f, 0.f};
        const int n0 = wid * 64;
        #pragma unroll
        for (int ks = 0; ks < 8; ++ks) {
            const int k0 = ks * 32 + lg * 8;
            short8 a[4], bf[4];
            #pragma unroll
            for (int mt = 0; mt < 4; ++mt)
                a[mt] = *reinterpret_cast<const short8*>(&Q[(mt * 16 + l15) * 264 + k0]);
            #pragma unroll
            for (int nt = 0; nt < 4; ++nt)
                bf[nt] = *reinterpret_cast<const short8*>(&W1T[(n0 + nt * 16 + l15) * 256 + k0]);
            #pragma unroll
            for (int mt = 0; mt < 4; ++mt)
                #pragma unroll
                for (int nt = 0; nt < 4; ++nt)
                    acc[mt][nt] = __builtin_amdgcn_mfma_f32_16x16x32_bf16(a[mt], bf[nt], acc[mt][nt], 0, 0, 0);
        }
        #pragma unroll
        for (int nt = 0; nt < 4; ++nt) {
            const int col = n0 + nt * 16 + l15;
            const float bv = b1[col];
            #pragma unroll
            for (int mt = 0; mt < 4; ++mt)
                #pragma unroll
                for (int r = 0; r < 4; ++r)
                    P[(mt * 16 + lg * 4 + r) * 264 + col] = f2bf(lrelu(acc[mt][nt][r] + bv));
        }
    }
    __syncthreads();

    // ---- layer 2 + aggregate: h2 = lrelu(h1 @ W2 + b2) [64x96], agg = colsum over j ----
    {
        f32x4 acc[4][2];
        #pragma unroll
        for (int mt = 0; mt < 4; ++mt) { acc[mt][0] = (f32x4){0.f,0.f,0.f,0.f}; acc[mt][1] = (f32x4){0.f,0.f,0.f,0.f}; }
        #pragma unroll
        for (int ks = 0; ks < 8; ++ks) {
            const int k0 = ks * 32 + lg * 8;
            short8 a[4], bf[2];
            #pragma unroll
            for (int mt = 0; mt < 4; ++mt)
                a[mt] = *reinterpret_cast<const short8*>(&P[(mt * 16 + l15) * 264 + k0]);
            #pragma unroll
            for (int nt = 0; nt < 2; ++nt)
                bf[nt] = *reinterpret_cast<const short8*>(&W2T[(wid * 16 + nt * 64 + l15) * 256 + k0]);
            #pragma unroll
            for (int mt = 0; mt < 4; ++mt)
                #pragma unroll
                for (int nt = 0; nt < 2; ++nt)
                    acc[mt][nt] = __builtin_amdgcn_mfma_f32_16x16x32_bf16(a[mt], bf[nt], acc[mt][nt], 0, 0, 0);
        }
        #pragma unroll
        for (int nt = 0; nt < 2; ++nt) {
            const int col = wid * 16 + nt * 64 + l15;
            const float bv = (col < 96) ? b2[col] : 0.f;
            float s = 0.f;
            #pragma unroll
            for (int mt = 0; mt < 4; ++mt)
                #pragma unroll
                for (int r = 0; r < 4; ++r)
                    s += lrelu(acc[mt][nt][r] + bv);
            s += __shfl_xor(s, 16);
            s += __shfl_xor(s, 32);
            if (lg == 0 && col < 96) agg[bid * 96 + col] = s;
        }
    }
}

// ---- node MLP: one block per 64 node-rows ----
__global__ __launch_bounds__(256, 2)
void node_kernel(const float* __restrict__ x, const float* __restrict__ agg,
                 const short* __restrict__ Wn0T, const short* __restrict__ Wn1T,
                 const float* __restrict__ bn0, const float* __restrict__ bn1,
                 float* __restrict__ out)
{
    __shared__ short A2[64 * 168];
    __shared__ short H[64 * 264];
    const int tid = threadIdx.x;
    const int lane = tid & 63, wid = tid >> 6;
    const int l15 = lane & 15, lg = lane >> 4;
    const int r0 = blockIdx.x * 64;

    // A2[j][0:96]=agg, [96:160]=x
    for (int t = tid; t < 64 * 160; t += 256) {
        int j = t / 160, c = t - j * 160;
        float v = (c < 96) ? agg[(r0 + j) * 96 + c] : x[(r0 + j) * 64 + (c - 96)];
        A2[j * 168 + c] = f2bf(v);
    }
    __syncthreads();

    // layer n0: H = lrelu(A2 @ Wn0 + bn0), K=160, N=256
    {
        f32x4 acc[4][4];
        #pragma unroll
        for (int mt = 0; mt < 4; ++mt)
            #pragma unroll
            for (int nt = 0; nt < 4; ++nt) acc[mt][nt] = (f32x4){0.f, 0.f, 0.f, 0.f};
        const int n0 = wid * 64;
        #pragma unroll
        for (int ks = 0; ks < 5; ++ks) {
            const int k0 = ks * 32 + lg * 8;
            short8 a[4], bf[4];
            #pragma unroll
            for (int mt = 0; mt < 4; ++mt)
                a[mt] = *reinterpret_cast<const short8*>(&A2[(mt * 16 + l15) * 168 + k0]);
            #pragma unroll
            for (int nt = 0; nt < 4; ++nt)
                bf[nt] = *reinterpret_cast<const short8*>(&Wn0T[(n0 + nt * 16 + l15) * 160 + k0]);
            #pragma unroll
            for (int mt = 0; mt < 4; ++mt)
                #pragma unroll
                for (int nt = 0; nt < 4; ++nt)
                    acc[mt][nt] = __builtin_amdgcn_mfma_f32_16x16x32_bf16(a[mt], bf[nt], acc[mt][nt], 0, 0, 0);
        }
        #pragma unroll
        for (int nt = 0; nt < 4; ++nt) {
            const int col = n0 + nt * 16 + l15;
            const float bv = bn0[col];
            #pragma unroll
            for (int mt = 0; mt < 4; ++mt)
                #pragma unroll
                for (int r = 0; r < 4; ++r)
                    H[(mt * 16 + lg * 4 + r) * 264 + col] = f2bf(lrelu(acc[mt][nt][r] + bv));
        }
    }
    __syncthreads();

    // layer n1 (linear): out = H @ Wn1 + bn1, K=256, N=64 (16 cols/wave)
    {
        f32x4 acc[4];
        #pragma unroll
        for (int mt = 0; mt < 4; ++mt) acc[mt] = (f32x4){0.f, 0.f, 0.f, 0.f};
        #pragma unroll
        for (int ks = 0; ks < 8; ++ks) {
            const int k0 = ks * 32 + lg * 8;
            short8 bf = *reinterpret_cast<const short8*>(&Wn1T[(wid * 16 + l15) * 256 + k0]);
            #pragma unroll
            for (int mt = 0; mt < 4; ++mt) {
                short8 a = *reinterpret_cast<const short8*>(&H[(mt * 16 + l15) * 264 + k0]);
                acc[mt] = __builtin_amdgcn_mfma_f32_16x16x32_bf16(a, bf, acc[mt], 0, 0, 0);
            }
        }
        const int col = wid * 16 + l15;
        const float bv = bn1[col];
        #pragma unroll
        for (int mt = 0; mt < 4; ++mt)
            #pragma unroll
            for (int r = 0; r < 4; ++r)
                out[(r0 + mt * 16 + lg * 4 + r) * 64 + col] = acc[mt][r] + bv;
    }
}

extern "C" void kernel_launch(void* const* d_in, const int* in_sizes, int n_in,
                              void* d_out, int out_size, void* d_ws, size_t ws_size,
                              hipStream_t stream) {
    (void)in_sizes; (void)n_in; (void)out_size; (void)ws_size;
    const float* x    = (const float*)d_in[0];
    const float* feW0 = (const float*)d_in[1];
    const float* feb0 = (const float*)d_in[2];
    const float* feW1 = (const float*)d_in[3];
    const float* feb1 = (const float*)d_in[4];
    const float* feW2 = (const float*)d_in[5];
    const float* feb2 = (const float*)d_in[6];
    const float* fnW0 = (const float*)d_in[7];
    const float* fnb0 = (const float*)d_in[8];
    const float* fnW1 = (const float*)d_in[9];
    const float* fnb1 = (const float*)d_in[10];

    char* ws = (char*)d_ws;
    short* W0T  = (short*)(ws + 0);        // 256*160*2 = 81920
    short* W1T  = (short*)(ws + 81920);    // 256*256*2 = 131072
    short* W2T  = (short*)(ws + 212992);   // 128*256*2 = 65536
    short* Wn0T = (short*)(ws + 278528);   // 256*160*2 = 81920
    short* Wn1T = (short*)(ws + 360448);   // 64*256*2  = 32768
    float* agg  = (float*)(ws + 393216);   // 8192*96*4 = 3145728

    hipLaunchKernelGGL(prep_kernel, dim3(64), dim3(256), 0, stream,
                       feW0, feW1, feW2, fnW0, fnW1, W0T, W1T, W2T, Wn0T, Wn1T);
    hipLaunchKernelGGL(edge_kernel, dim3(8192), dim3(256), 0, stream,
                       x, W0T, W1T, W2T, feb0, feb1, feb2, agg);
    hipLaunchKernelGGL(node_kernel, dim3(128), dim3(256), 0, stream,
                       x, agg, Wn0T, Wn1T, fnb0, fnb1, (float*)d_out);
}

// Round 2
// 216.667 us; speedup vs baseline: 1.3286x; 1.3286x over previous
//
#include <hip/hip_runtime.h>

#define ALPHA 0.2f

typedef __attribute__((ext_vector_type(8))) short short8;
typedef __attribute__((ext_vector_type(4))) float f32x4;
typedef __attribute__((ext_vector_type(2))) unsigned int u32x2;

__device__ __forceinline__ short f2bf(float f) {
    unsigned u = __builtin_bit_cast(unsigned, f);
    u += 0x7fffu + ((u >> 16) & 1u);   // round-to-nearest-even
    return (short)(u >> 16);
}
__device__ __forceinline__ unsigned pack2(float a, float b) {
    return ((unsigned)(unsigned short)f2bf(a)) | (((unsigned)(unsigned short)f2bf(b)) << 16);
}
__device__ __forceinline__ float lrelu(float v) { return v > 0.f ? v : ALPHA * v; }

// ---- weight prep ----
// W1F/W2F/W0uvF: fragment-linear bf16 for A-operand (feat = M dim):
//   idx = ((mt*KS + ks)*64 + lane)*8 + e ; feat = mt*16 + (lane&15); k = ks*32 + (lane>>4)*8 + e
// Wn0T/Wn1T: [N][Kpad] layouts for the (unchanged) node kernel.
__global__ void prep_kernel(const float* __restrict__ feW0, const float* __restrict__ feW1,
                            const float* __restrict__ feW2, const float* __restrict__ fnW0,
                            const float* __restrict__ fnW1,
                            short* __restrict__ W1F, short* __restrict__ W2F,
                            short* __restrict__ W0uvF,
                            short* __restrict__ Wn0T, short* __restrict__ Wn1T)
{
    const int tid = blockIdx.x * blockDim.x + threadIdx.x;
    const int T = gridDim.x * blockDim.x;
    // W1F: 256 feats x 256 k  (mt<16, ks<8)
    for (int t = tid; t < 65536; t += T) {
        int e = t & 7, lane = (t >> 3) & 63, ks = (t >> 9) & 7, mt = t >> 12;
        int feat = mt * 16 + (lane & 15), k = ks * 32 + (lane >> 4) * 8 + e;
        W1F[t] = f2bf(feW1[k * 256 + feat]);
    }
    // W2F: 128 feats x 256 k (mt<8, ks<8); feat>=96 zero
    for (int t = tid; t < 32768; t += T) {
        int e = t & 7, lane = (t >> 3) & 63, ks = (t >> 9) & 7, mt = t >> 12;
        int feat = mt * 16 + (lane & 15), k = ks * 32 + (lane >> 4) * 8 + e;
        W2F[t] = f2bf(feat < 96 ? feW2[k * 96 + feat] : 0.f);
    }
    // W0uvF: 512 feats x 64 k (mt<32, ks<2); feat<256 -> W0a col, else W0b col
    for (int t = tid; t < 32768; t += T) {
        int e = t & 7, lane = (t >> 3) & 63, ks = (t >> 9) & 1, mt = t >> 10;
        int feat = mt * 16 + (lane & 15), k = ks * 32 + (lane >> 4) * 8 + e;
        float val = (feat < 256) ? feW0[k * 256 + feat] : feW0[(64 + k) * 256 + (feat - 256)];
        W0uvF[t] = f2bf(val);
    }
    // Wn0T: [256][160] from fnW0 [160][256]
    for (int t = tid; t < 256 * 160; t += T) { int n = t / 160, k = t - n * 160; Wn0T[t] = f2bf(fnW0[k * 256 + n]); }
    // Wn1T: [64][256] from fnW1 [256][64]
    for (int t = tid; t < 64 * 256; t += T) { int n = t >> 8, k = t & 255; Wn1T[t] = f2bf(fnW1[k * 64 + n]); }
}

// ---- u,v precompute: u[r] = x[r]·W0a, v[r] = x[r]·W0b  (f32 out) ----
__global__ __launch_bounds__(256, 4)
void uv_kernel(const float* __restrict__ x, const short* __restrict__ W0uvF,
               float* __restrict__ u, float* __restrict__ v)
{
    __shared__ __align__(16) short xb[4096];   // [64][64] bf16, XOR-swizzled
    const int tid = threadIdx.x;
    const int lane = tid & 63, wid = tid >> 6;
    const int l15 = lane & 15, lg = lane >> 4;
    const int r0 = blockIdx.x * 64;

    for (int t = tid; t < 4096; t += 256) {
        int row = t >> 6;
        int byte = (t * 2) ^ ((row & 7) << 4);
        *(short*)((char*)xb + byte) = f2bf(x[r0 * 64 + t]);
    }
    __syncthreads();

    #pragma unroll
    for (int pair = 0; pair < 4; ++pair) {
        const int mt0 = wid * 8 + pair * 2;
        f32x4 acc[2][4];
        #pragma unroll
        for (int m = 0; m < 2; ++m)
            #pragma unroll
            for (int nt = 0; nt < 4; ++nt) acc[m][nt] = (f32x4){0.f, 0.f, 0.f, 0.f};
        #pragma unroll
        for (int ks = 0; ks < 2; ++ks) {
            short8 a[2], bf[4];
            #pragma unroll
            for (int m = 0; m < 2; ++m)
                a[m] = *(const short8*)&W0uvF[(((mt0 + m) * 2 + ks) * 64 + lane) * 8];
            #pragma unroll
            for (int nt = 0; nt < 4; ++nt) {
                int row = nt * 16 + l15;
                int byte = (row * 128 + (ks * 32 + lg * 8) * 2) ^ ((row & 7) << 4);
                bf[nt] = *(const short8*)((char*)xb + byte);
            }
            #pragma unroll
            for (int m = 0; m < 2; ++m)
                #pragma unroll
                for (int nt = 0; nt < 4; ++nt)
                    acc[m][nt] = __builtin_amdgcn_mfma_f32_16x16x32_bf16(a[m], bf[nt], acc[m][nt], 0, 0, 0);
        }
        #pragma unroll
        for (int m = 0; m < 2; ++m) {
            int feat0 = (mt0 + m) * 16 + lg * 4;
            #pragma unroll
            for (int nt = 0; nt < 4; ++nt) {
                int R = r0 + nt * 16 + l15;
                float* dst = (feat0 < 256) ? &u[R * 256 + feat0] : &v[R * 256 + (feat0 - 256)];
                *(f32x4*)dst = acc[m][nt];
            }
        }
    }
}

// ---- edge MLP + aggregation: one block per (b,i), 512 threads ----
__global__ __launch_bounds__(512, 4)
void edge_kernel(const float* __restrict__ x, const float* __restrict__ feW0,
                 const float* __restrict__ b0v,
                 const short* __restrict__ W1F, const short* __restrict__ W2F,
                 const float* __restrict__ b1v, const float* __restrict__ b2v,
                 const float* __restrict__ u, const float* __restrict__ v,
                 float* __restrict__ agg)
{
    __shared__ __align__(16) char smem[65536];
    // h0:   [0, 32768)        bf16 [64][256], XOR-swizzled
    // h1:   [32768, 65536)    bf16 [64][256], XOR-swizzled  (written in L1 epilogue)
    // aliases inside h1 region (all dead before h1 is written):
    float* xs     = (float*)(smem + 32768);   // f32 [64][68]   (17408 B)
    float* dist_s = (float*)(smem + 50176);   // f32 [64]
    float* ub     = (float*)(smem + 50432);   // f32 [256]  u_i + b0
    float* wd     = (float*)(smem + 51456);   // f32 [256]  W0 dist row
    char* h1 = smem + 32768;

    const int tid = threadIdx.x;
    const int lane = tid & 63, wid = tid >> 6;
    const int l15 = lane & 15, lg = lane >> 4;
    const int bid = blockIdx.x;
    const int b = bid >> 6, i = bid & 63;

    // phase 0: stage x[b] (f32) + ub/wd
    {
        const float* xb = x + b * 4096;
        int j = tid >> 3, f0 = (tid & 7) * 8;
        *(f32x4*)&xs[j * 68 + f0]     = *(const f32x4*)&xb[j * 64 + f0];
        *(f32x4*)&xs[j * 68 + f0 + 4] = *(const f32x4*)&xb[j * 64 + f0 + 4];
        if (tid < 256) {
            ub[tid] = u[(b * 64 + i) * 256 + tid] + b0v[tid];
            wd[tid] = feW0[128 * 256 + tid];
        }
    }
    __syncthreads();

    // phase 1: dist[j] = ||x_j - x_i + 1e-12||
    {
        int j = tid >> 3, f0 = (tid & 7) * 8;
        float ss = 0.f;
        #pragma unroll
        for (int f = 0; f < 8; ++f) {
            float d = xs[j * 68 + f0 + f] - xs[i * 68 + f0 + f] + 1e-12f;
            ss += d * d;
        }
        ss += __shfl_xor(ss, 1); ss += __shfl_xor(ss, 2); ss += __shfl_xor(ss, 4);
        if ((tid & 7) == 0) dist_s[j] = sqrtf(ss);
    }
    __syncthreads();

    // phase 2: h0[j][c] = lrelu(ub[c] + v[b,j][c] + dist_j*wd[c])
    {
        int j = tid >> 3, c0 = (tid & 7) * 32;
        float dj = dist_s[j];
        const float* gv = v + (b * 64 + j) * 256;
        #pragma unroll
        for (int e = 0; e < 8; ++e) {
            int c = c0 + e * 4;
            f32x4 vv = *(const f32x4*)&gv[c];
            f32x4 uu = *(const f32x4*)&ub[c];
            f32x4 ww = *(const f32x4*)&wd[c];
            float q0 = lrelu(uu[0] + vv[0] + dj * ww[0]);
            float q1 = lrelu(uu[1] + vv[1] + dj * ww[1]);
            float q2 = lrelu(uu[2] + vv[2] + dj * ww[2]);
            float q3 = lrelu(uu[3] + vv[3] + dj * ww[3]);
            u32x2 pv; pv[0] = pack2(q0, q1); pv[1] = pack2(q2, q3);
            int byte = (j * 512 + c * 2) ^ ((j & 7) << 4);
            *(u32x2*)(smem + byte) = pv;
        }
    }
    __syncthreads();

    // phase 3: layer1  h1 = lrelu(h0 @ W1 + b1); W as A-operand (feat=M), h0 as B (j=N)
    {
        f32x4 acc[2][4];
        #pragma unroll
        for (int m = 0; m < 2; ++m)
            #pragma unroll
            for (int nt = 0; nt < 4; ++nt) acc[m][nt] = (f32x4){0.f, 0.f, 0.f, 0.f};
        #pragma unroll
        for (int ks = 0; ks < 8; ++ks) {
            short8 a[2], bf[4];
            #pragma unroll
            for (int m = 0; m < 2; ++m)
                a[m] = *(const short8*)&W1F[(((wid * 2 + m) * 8 + ks) * 64 + lane) * 8];
            #pragma unroll
            for (int nt = 0; nt < 4; ++nt) {
                int j = nt * 16 + l15;
                int byte = (j * 512 + (ks * 32 + lg * 8) * 2) ^ ((j & 7) << 4);
                bf[nt] = *(const short8*)(smem + byte);
            }
            #pragma unroll
            for (int m = 0; m < 2; ++m)
                #pragma unroll
                for (int nt = 0; nt < 4; ++nt)
                    acc[m][nt] = __builtin_amdgcn_mfma_f32_16x16x32_bf16(a[m], bf[nt], acc[m][nt], 0, 0, 0);
        }
        #pragma unroll
        for (int m = 0; m < 2; ++m) {
            int f0 = wid * 32 + m * 16 + lg * 4;
            f32x4 bb = *(const f32x4*)&b1v[f0];
            #pragma unroll
            for (int nt = 0; nt < 4; ++nt) {
                int j = nt * 16 + l15;
                float q0 = lrelu(acc[m][nt][0] + bb[0]);
                float q1 = lrelu(acc[m][nt][1] + bb[1]);
                float q2 = lrelu(acc[m][nt][2] + bb[2]);
                float q3 = lrelu(acc[m][nt][3] + bb[3]);
                u32x2 pv; pv[0] = pack2(q0, q1); pv[1] = pack2(q2, q3);
                int byte = (j * 512 + f0 * 2) ^ ((j & 7) << 4);
                *(u32x2*)(h1 + byte) = pv;
            }
        }
    }
    __syncthreads();

    // phase 4: layer2 + aggregate over j. waves 0..5 cover feats 0..95.
    if (wid < 6) {
        f32x4 acc[4];
        #pragma unroll
        for (int nt = 0; nt < 4; ++nt) acc[nt] = (f32x4){0.f, 0.f, 0.f, 0.f};
        #pragma unroll
        for (int ks = 0; ks < 8; ++ks) {
            short8 a = *(const short8*)&W2F[((wid * 8 + ks) * 64 + lane) * 8];
            #pragma unroll
            for (int nt = 0; nt < 4; ++nt) {
                int j = nt * 16 + l15;
                int byte = (j * 512 + (ks * 32 + lg * 8) * 2) ^ ((j & 7) << 4);
                short8 bf = *(const short8*)(h1 + byte);
                acc[nt] = __builtin_amdgcn_mfma_f32_16x16x32_bf16(a, bf, acc[nt], 0, 0, 0);
            }
        }
        const int f0 = wid * 16 + lg * 4;
        f32x4 bb = *(const f32x4*)&b2v[f0];
        f32x4 s = (f32x4){0.f, 0.f, 0.f, 0.f};
        #pragma unroll
        for (int nt = 0; nt < 4; ++nt)
            #pragma unroll
            for (int r = 0; r < 4; ++r)
                s[r] += lrelu(acc[nt][r] + bb[r]);
        #pragma unroll
        for (int r = 0; r < 4; ++r) {
            float t = s[r];
            t += __shfl_xor(t, 1); t += __shfl_xor(t, 2);
            t += __shfl_xor(t, 4); t += __shfl_xor(t, 8);
            s[r] = t;
        }
        if (l15 == 0) *(f32x4*)&agg[bid * 96 + f0] = s;
    }
}

// ---- node MLP: one block per 64 node-rows (unchanged from R0, passed) ----
__global__ __launch_bounds__(256, 2)
void node_kernel(const float* __restrict__ x, const float* __restrict__ agg,
                 const short* __restrict__ Wn0T, const short* __restrict__ Wn1T,
                 const float* __restrict__ bn0, const float* __restrict__ bn1,
                 float* __restrict__ out)
{
    __shared__ short A2[64 * 168];
    __shared__ short H[64 * 264];
    const int tid = threadIdx.x;
    const int lane = tid & 63, wid = tid >> 6;
    const int l15 = lane & 15, lg = lane >> 4;
    const int r0 = blockIdx.x * 64;

    for (int t = tid; t < 64 * 160; t += 256) {
        int j = t / 160, c = t - j * 160;
        float vv = (c < 96) ? agg[(r0 + j) * 96 + c] : x[(r0 + j) * 64 + (c - 96)];
        A2[j * 168 + c] = f2bf(vv);
    }
    __syncthreads();

    {
        f32x4 acc[4][4];
        #pragma unroll
        for (int mt = 0; mt < 4; ++mt)
            #pragma unroll
            for (int nt = 0; nt < 4; ++nt) acc[mt][nt] = (f32x4){0.f, 0.f, 0.f, 0.f};
        const int n0 = wid * 64;
        #pragma unroll
        for (int ks = 0; ks < 5; ++ks) {
            const int k0 = ks * 32 + lg * 8;
            short8 a[4], bf[4];
            #pragma unroll
            for (int mt = 0; mt < 4; ++mt)
                a[mt] = *reinterpret_cast<const short8*>(&A2[(mt * 16 + l15) * 168 + k0]);
            #pragma unroll
            for (int nt = 0; nt < 4; ++nt)
                bf[nt] = *reinterpret_cast<const short8*>(&Wn0T[(n0 + nt * 16 + l15) * 160 + k0]);
            #pragma unroll
            for (int mt = 0; mt < 4; ++mt)
                #pragma unroll
                for (int nt = 0; nt < 4; ++nt)
                    acc[mt][nt] = __builtin_amdgcn_mfma_f32_16x16x32_bf16(a[mt], bf[nt], acc[mt][nt], 0, 0, 0);
        }
        #pragma unroll
        for (int nt = 0; nt < 4; ++nt) {
            const int col = n0 + nt * 16 + l15;
            const float bv = bn0[col];
            #pragma unroll
            for (int mt = 0; mt < 4; ++mt)
                #pragma unroll
                for (int r = 0; r < 4; ++r)
                    H[(mt * 16 + lg * 4 + r) * 264 + col] = f2bf(lrelu(acc[mt][nt][r] + bv));
        }
    }
    __syncthreads();

    {
        f32x4 acc[4];
        #pragma unroll
        for (int mt = 0; mt < 4; ++mt) acc[mt] = (f32x4){0.f, 0.f, 0.f, 0.f};
        #pragma unroll
        for (int ks = 0; ks < 8; ++ks) {
            const int k0 = ks * 32 + lg * 8;
            short8 bf = *reinterpret_cast<const short8*>(&Wn1T[(wid * 16 + l15) * 256 + k0]);
            #pragma unroll
            for (int mt = 0; mt < 4; ++mt) {
                short8 a = *reinterpret_cast<const short8*>(&H[(mt * 16 + l15) * 264 + k0]);
                acc[mt] = __builtin_amdgcn_mfma_f32_16x16x32_bf16(a, bf, acc[mt], 0, 0, 0);
            }
        }
        const int col = wid * 16 + l15;
        const float bv = bn1[col];
        #pragma unroll
        for (int mt = 0; mt < 4; ++mt)
            #pragma unroll
            for (int r = 0; r < 4; ++r)
                out[(r0 + mt * 16 + lg * 4 + r) * 64 + col] = acc[mt][r] + bv;
    }
}

extern "C" void kernel_launch(void* const* d_in, const int* in_sizes, int n_in,
                              void* d_out, int out_size, void* d_ws, size_t ws_size,
                              hipStream_t stream) {
    (void)in_sizes; (void)n_in; (void)out_size; (void)ws_size;
    const float* x    = (const float*)d_in[0];
    const float* feW0 = (const float*)d_in[1];
    const float* feb0 = (const float*)d_in[2];
    const float* feW1 = (const float*)d_in[3];
    const float* feb1 = (const float*)d_in[4];
    const float* feW2 = (const float*)d_in[5];
    const float* feb2 = (const float*)d_in[6];
    const float* fnW0 = (const float*)d_in[7];
    const float* fnb0 = (const float*)d_in[8];
    const float* fnW1 = (const float*)d_in[9];
    const float* fnb1 = (const float*)d_in[10];

    char* ws = (char*)d_ws;
    short* W1F   = (short*)(ws + 0);          // 65536*2  = 131072
    short* W2F   = (short*)(ws + 131072);     // 32768*2  = 65536
    short* W0uvF = (short*)(ws + 196608);     // 32768*2  = 65536
    short* Wn0T  = (short*)(ws + 262144);     // 40960*2  = 81920
    short* Wn1T  = (short*)(ws + 344064);     // 16384*2  = 32768
    float* agg   = (float*)(ws + 376832);     // 8192*96*4 = 3145728
    float* u     = (float*)(ws + 3522560);    // 8192*256*4 = 8388608
    float* v     = (float*)(ws + 11911168);   // 8388608  -> total ~20.3 MB

    hipLaunchKernelGGL(prep_kernel, dim3(64), dim3(256), 0, stream,
                       feW0, feW1, feW2, fnW0, fnW1, W1F, W2F, W0uvF, Wn0T, Wn1T);
    hipLaunchKernelGGL(uv_kernel, dim3(128), dim3(256), 0, stream,
                       x, W0uvF, u, v);
    hipLaunchKernelGGL(edge_kernel, dim3(8192), dim3(512), 0, stream,
                       x, feW0, feb0, W1F, W2F, feb1, feb2, u, v, agg);
    hipLaunchKernelGGL(node_kernel, dim3(128), dim3(256), 0, stream,
                       x, agg, Wn0T, Wn1T, fnb0, fnb1, (float*)d_out);
}

// Round 3
// 163.358 us; speedup vs baseline: 1.7621x; 1.3263x over previous
//
#include <hip/hip_runtime.h>

#define ALPHA 0.2f

typedef __attribute__((ext_vector_type(8))) short short8;
typedef __attribute__((ext_vector_type(4))) float f32x4;
typedef __attribute__((ext_vector_type(2))) unsigned int u32x2;
typedef __attribute__((ext_vector_type(4))) unsigned int u32x4;

__device__ __forceinline__ short f2bf(float f) {
    unsigned u = __builtin_bit_cast(unsigned, f);
    u += 0x7fffu + ((u >> 16) & 1u);   // RNE
    return (short)(u >> 16);
}
// round-half-up pack of two f32 -> packed bf16x2 (cheap: 2 add + shift/merge)
__device__ __forceinline__ unsigned pack2(float a, float b) {
    unsigned ua = __builtin_bit_cast(unsigned, a) + 0x8000u;
    unsigned ub = __builtin_bit_cast(unsigned, b) + 0x8000u;
    return (ua >> 16) | (ub & 0xffff0000u);
}
__device__ __forceinline__ float bf2f(short s) {
    return __builtin_bit_cast(float, ((unsigned)(unsigned short)s) << 16);
}
__device__ __forceinline__ float lrelu(float v) { return fmaxf(v, ALPHA * v); }

// ---- weight prep (unchanged from R1) ----
__global__ void prep_kernel(const float* __restrict__ feW0, const float* __restrict__ feW1,
                            const float* __restrict__ feW2, const float* __restrict__ fnW0,
                            const float* __restrict__ fnW1,
                            short* __restrict__ W1F, short* __restrict__ W2F,
                            short* __restrict__ W0uvF,
                            short* __restrict__ Wn0T, short* __restrict__ Wn1T)
{
    const int tid = blockIdx.x * blockDim.x + threadIdx.x;
    const int T = gridDim.x * blockDim.x;
    // W1F: fragment-linear: idx=((mt*8+ks)*64+lane)*8+e ; feat=mt*16+(lane&15); k=ks*32+(lane>>4)*8+e
    for (int t = tid; t < 65536; t += T) {
        int e = t & 7, lane = (t >> 3) & 63, ks = (t >> 9) & 7, mt = t >> 12;
        int feat = mt * 16 + (lane & 15), k = ks * 32 + (lane >> 4) * 8 + e;
        W1F[t] = f2bf(feW1[k * 256 + feat]);
    }
    // W2F: 128 feats (>=96 zero) x 256 k
    for (int t = tid; t < 32768; t += T) {
        int e = t & 7, lane = (t >> 3) & 63, ks = (t >> 9) & 7, mt = t >> 12;
        int feat = mt * 16 + (lane & 15), k = ks * 32 + (lane >> 4) * 8 + e;
        W2F[t] = f2bf(feat < 96 ? feW2[k * 96 + feat] : 0.f);
    }
    // W0uvF: 512 feats x 64 k; feat<256 -> W0a col, else W0b col
    for (int t = tid; t < 32768; t += T) {
        int e = t & 7, lane = (t >> 3) & 63, ks = (t >> 9) & 1, mt = t >> 10;
        int feat = mt * 16 + (lane & 15), k = ks * 32 + (lane >> 4) * 8 + e;
        float val = (feat < 256) ? feW0[k * 256 + feat] : feW0[(64 + k) * 256 + (feat - 256)];
        W0uvF[t] = f2bf(val);
    }
    for (int t = tid; t < 256 * 160; t += T) { int n = t / 160, k = t - n * 160; Wn0T[t] = f2bf(fnW0[k * 256 + n]); }
    for (int t = tid; t < 64 * 256; t += T) { int n = t >> 8, k = t & 255; Wn1T[t] = f2bf(fnW1[k * 64 + n]); }
}

// ---- u,v precompute (unchanged from R1) ----
__global__ __launch_bounds__(256, 4)
void uv_kernel(const float* __restrict__ x, const short* __restrict__ W0uvF,
               float* __restrict__ u, float* __restrict__ v)
{
    __shared__ __align__(16) short xb[4096];
    const int tid = threadIdx.x;
    const int lane = tid & 63, wid = tid >> 6;
    const int l15 = lane & 15, lg = lane >> 4;
    const int r0 = blockIdx.x * 64;

    for (int t = tid; t < 4096; t += 256) {
        int row = t >> 6;
        int byte = (t * 2) ^ ((row & 7) << 4);
        *(short*)((char*)xb + byte) = f2bf(x[r0 * 64 + t]);
    }
    __syncthreads();

    #pragma unroll
    for (int pair = 0; pair < 4; ++pair) {
        const int mt0 = wid * 8 + pair * 2;
        f32x4 acc[2][4];
        #pragma unroll
        for (int m = 0; m < 2; ++m)
            #pragma unroll
            for (int nt = 0; nt < 4; ++nt) acc[m][nt] = (f32x4){0.f, 0.f, 0.f, 0.f};
        #pragma unroll
        for (int ks = 0; ks < 2; ++ks) {
            short8 a[2], bf[4];
            #pragma unroll
            for (int m = 0; m < 2; ++m)
                a[m] = *(const short8*)&W0uvF[(((mt0 + m) * 2 + ks) * 64 + lane) * 8];
            #pragma unroll
            for (int nt = 0; nt < 4; ++nt) {
                int row = nt * 16 + l15;
                int byte = (row * 128 + (ks * 32 + lg * 8) * 2) ^ ((row & 7) << 4);
                bf[nt] = *(const short8*)((char*)xb + byte);
            }
            #pragma unroll
            for (int m = 0; m < 2; ++m)
                #pragma unroll
                for (int nt = 0; nt < 4; ++nt)
                    acc[m][nt] = __builtin_amdgcn_mfma_f32_16x16x32_bf16(a[m], bf[nt], acc[m][nt], 0, 0, 0);
        }
        #pragma unroll
        for (int m = 0; m < 2; ++m) {
            int feat0 = (mt0 + m) * 16 + lg * 4;
            #pragma unroll
            for (int nt = 0; nt < 4; ++nt) {
                int R = r0 + nt * 16 + l15;
                float* dst = (feat0 < 256) ? &u[R * 256 + feat0] : &v[R * 256 + (feat0 - 256)];
                *(f32x4*)dst = acc[m][nt];
            }
        }
    }
}

// ---- edge MLP + aggregation: one block per (b, 16-i group); weight-stationary ----
__global__ __launch_bounds__(512, 2)
void edge_kernel(const float* __restrict__ x, const float* __restrict__ feW0,
                 const float* __restrict__ b0v, const float* __restrict__ b1v,
                 const float* __restrict__ b2v,
                 const short* __restrict__ W1F, const short* __restrict__ W2F,
                 const float* __restrict__ u, const float* __restrict__ v,
                 float* __restrict__ agg)
{
    __shared__ __align__(16) char smem[119808];
    char* vb = smem;                         // bf16 [64][256] XOR-swz   (32768)
    char* h0 = smem + 32768;                 // bf16 [64][256] XOR-swz   (32768)
    char* h1 = smem + 65536;                 // bf16 [64][256] XOR-swz   (32768)
    float* ub_f = (float*)(smem + 98304);    // f32 [16][64 quads] swz   (16384)
    float* wd_f = (float*)(smem + 114688);   // f32 [64 quads] swz       (1024)
    float* dist = (float*)(smem + 115712);   // f32 [16][64]             (4096)
    float* xs   = (float*)(smem + 65536);    // alias h1: f32 [64][68]   (17408)

    const int tid = threadIdx.x;
    const int lane = tid & 63, wid = tid >> 6;
    const int l15 = lane & 15, lg = lane >> 4;
    const int j8 = tid >> 3, p8 = tid & 7;
    const int b = blockIdx.x >> 2, i0 = (blockIdx.x & 3) * 16;

    // ---- weight fragments -> registers (once per block, coalesced) ----
    short8 a1[2][8];
    #pragma unroll
    for (int m = 0; m < 2; ++m)
        #pragma unroll
        for (int ks = 0; ks < 8; ++ks)
            a1[m][ks] = *(const short8*)&W1F[(((wid * 2 + m) * 8 + ks) * 64 + lane) * 8];
    short8 a2[8];
    #pragma unroll
    for (int ks = 0; ks < 8; ++ks)
        a2[ks] = *(const short8*)&W2F[((wid * 8 + ks) * 64 + lane) * 8];
    f32x4 bb1[2];
    bb1[0] = *(const f32x4*)&b1v[wid * 32 + lg * 4];
    bb1[1] = *(const f32x4*)&b1v[wid * 32 + 16 + lg * 4];
    f32x4 bb2 = (f32x4){0.f, 0.f, 0.f, 0.f};
    if (wid < 6) bb2 = *(const f32x4*)&b2v[wid * 16 + lg * 4];

    // ---- prologue staging ----
    {   // xs: x[b] f32 [64][68]
        const float* xb = x + b * 4096;
        *(f32x4*)&xs[j8 * 68 + p8 * 8]     = *(const f32x4*)&xb[j8 * 64 + p8 * 8];
        *(f32x4*)&xs[j8 * 68 + p8 * 8 + 4] = *(const f32x4*)&xb[j8 * 64 + p8 * 8 + 4];
    }
    {   // vb: v[b] -> bf16, XOR-swizzled 16B chunks
        const float* gv = v + (b * 64 + j8) * 256;
        #pragma unroll
        for (int e = 0; e < 4; ++e) {
            int c0 = p8 * 32 + e * 8;
            f32x4 v0 = *(const f32x4*)&gv[c0];
            f32x4 v1 = *(const f32x4*)&gv[c0 + 4];
            u32x4 pk;
            pk[0] = pack2(v0[0], v0[1]); pk[1] = pack2(v0[2], v0[3]);
            pk[2] = pack2(v1[0], v1[1]); pk[3] = pack2(v1[2], v1[3]);
            *(u32x4*)(vb + ((j8 * 512 + c0 * 2) ^ ((j8 & 7) << 4))) = pk;
        }
    }
    {   // ub: u[b, i0+ii] + b0, quad-swizzled (q ^= q>>3)
        int ii = tid >> 5, c0 = (tid & 31) * 8;
        const float* gu = u + (b * 64 + i0 + ii) * 256 + c0;
        f32x4 u0 = *(const f32x4*)&gu[0];
        f32x4 u1 = *(const f32x4*)&gu[4];
        u0 += *(const f32x4*)&b0v[c0];
        u1 += *(const f32x4*)&b0v[c0 + 4];
        int q = c0 >> 2;
        *(f32x4*)&ub_f[(ii * 64 + (q ^ (q >> 3))) * 4] = u0;
        *(f32x4*)&ub_f[(ii * 64 + ((q + 1) ^ ((q + 1) >> 3))) * 4] = u1;
    }
    if (tid < 64) {  // wd: feW0 dist-row, quad-swizzled
        f32x4 w0 = *(const f32x4*)&feW0[128 * 256 + tid * 4];
        *(f32x4*)&wd_f[(tid ^ (tid >> 3)) * 4] = w0;
    }
    __syncthreads();

    // ---- dist[ii][j] for the block's 16 i's ----
    {
        f32x4 xj0 = *(const f32x4*)&xs[j8 * 68 + p8 * 8];
        f32x4 xj1 = *(const f32x4*)&xs[j8 * 68 + p8 * 8 + 4];
        #pragma unroll
        for (int ii = 0; ii < 16; ++ii) {
            const float* xi = &xs[(i0 + ii) * 68 + p8 * 8];
            f32x4 xi0 = *(const f32x4*)&xi[0];
            f32x4 xi1 = *(const f32x4*)&xi[4];
            float ss = 0.f;
            #pragma unroll
            for (int r = 0; r < 4; ++r) {
                float d0 = xj0[r] - xi0[r] + 1e-12f;
                float d1 = xj1[r] - xi1[r] + 1e-12f;
                ss += d0 * d0 + d1 * d1;
            }
            ss += __shfl_xor(ss, 1); ss += __shfl_xor(ss, 2); ss += __shfl_xor(ss, 4);
            if (p8 == 0) dist[ii * 64 + j8] = sqrtf(ss);
        }
    }
    __syncthreads();

    // build h0 for node i = i0+ii_ (conflict-free swizzled reads)
    #define BUILD(ii_) do { \
        float dj = dist[(ii_) * 64 + j8]; \
        _Pragma("unroll") \
        for (int e = 0; e < 4; ++e) { \
            int c0 = p8 * 32 + e * 8; \
            int q0 = p8 * 8 + e * 2; \
            short8 vr = *(const short8*)(vb + ((j8 * 512 + c0 * 2) ^ ((j8 & 7) << 4))); \
            f32x4 uu0 = *(const f32x4*)&ub_f[((ii_) * 64 + (q0 ^ p8)) * 4]; \
            f32x4 uu1 = *(const f32x4*)&ub_f[((ii_) * 64 + ((q0 + 1) ^ p8)) * 4]; \
            f32x4 ww0 = *(const f32x4*)&wd_f[(q0 ^ p8) * 4]; \
            f32x4 ww1 = *(const f32x4*)&wd_f[((q0 + 1) ^ p8) * 4]; \
            float t0 = lrelu(uu0[0] + bf2f(vr[0]) + dj * ww0[0]); \
            float t1 = lrelu(uu0[1] + bf2f(vr[1]) + dj * ww0[1]); \
            float t2 = lrelu(uu0[2] + bf2f(vr[2]) + dj * ww0[2]); \
            float t3 = lrelu(uu0[3] + bf2f(vr[3]) + dj * ww0[3]); \
            float t4 = lrelu(uu1[0] + bf2f(vr[4]) + dj * ww1[0]); \
            float t5 = lrelu(uu1[1] + bf2f(vr[5]) + dj * ww1[1]); \
            float t6 = lrelu(uu1[2] + bf2f(vr[6]) + dj * ww1[2]); \
            float t7 = lrelu(uu1[3] + bf2f(vr[7]) + dj * ww1[3]); \
            u32x4 pk; \
            pk[0] = pack2(t0, t1); pk[1] = pack2(t2, t3); \
            pk[2] = pack2(t4, t5); pk[3] = pack2(t6, t7); \
            *(u32x4*)(h0 + ((j8 * 512 + c0 * 2) ^ ((j8 & 7) << 4))) = pk; \
        } \
    } while (0)

    BUILD(0);
    __syncthreads();

    float* aggrow = agg + (b * 64 + i0) * 96;
    for (int ii = 0; ii < 16; ++ii) {
        // ---- phase A: GEMM1  h1 = lrelu(W1 @ h0 + b1) ----
        {
            f32x4 acc[2][4];
            #pragma unroll
            for (int m = 0; m < 2; ++m)
                #pragma unroll
                for (int nt = 0; nt < 4; ++nt) acc[m][nt] = (f32x4){0.f, 0.f, 0.f, 0.f};
            #pragma unroll
            for (int ks = 0; ks < 8; ++ks) {
                short8 bfr[4];
                #pragma unroll
                for (int nt = 0; nt < 4; ++nt) {
                    int j = nt * 16 + l15;
                    bfr[nt] = *(const short8*)(h0 + ((j * 512 + (ks * 32 + lg * 8) * 2) ^ ((j & 7) << 4)));
                }
                #pragma unroll
                for (int m = 0; m < 2; ++m)
                    #pragma unroll
                    for (int nt = 0; nt < 4; ++nt)
                        acc[m][nt] = __builtin_amdgcn_mfma_f32_16x16x32_bf16(a1[m][ks], bfr[nt], acc[m][nt], 0, 0, 0);
            }
            #pragma unroll
            for (int m = 0; m < 2; ++m) {
                int f0 = wid * 32 + m * 16 + lg * 4;
                #pragma unroll
                for (int nt = 0; nt < 4; ++nt) {
                    int j = nt * 16 + l15;
                    float q0 = lrelu(acc[m][nt][0] + bb1[m][0]);
                    float q1 = lrelu(acc[m][nt][1] + bb1[m][1]);
                    float q2 = lrelu(acc[m][nt][2] + bb1[m][2]);
                    float q3 = lrelu(acc[m][nt][3] + bb1[m][3]);
                    u32x2 pv; pv[0] = pack2(q0, q1); pv[1] = pack2(q2, q3);
                    *(u32x2*)(h1 + ((j * 512 + f0 * 2) ^ ((j & 7) << 4))) = pv;
                }
            }
        }
        __syncthreads();
        // ---- phase B: GEMM2 + aggregate (waves 0-5)  ||  build h0(ii+1) (all waves) ----
        if (ii < 15) BUILD(ii + 1);
        if (wid < 6) {
            f32x4 acc2[4];
            #pragma unroll
            for (int nt = 0; nt < 4; ++nt) acc2[nt] = (f32x4){0.f, 0.f, 0.f, 0.f};
            #pragma unroll
            for (int ks = 0; ks < 8; ++ks) {
                #pragma unroll
                for (int nt = 0; nt < 4; ++nt) {
                    int j = nt * 16 + l15;
                    short8 bfr = *(const short8*)(h1 + ((j * 512 + (ks * 32 + lg * 8) * 2) ^ ((j & 7) << 4)));
                    acc2[nt] = __builtin_amdgcn_mfma_f32_16x16x32_bf16(a2[ks], bfr, acc2[nt], 0, 0, 0);
                }
            }
            f32x4 s = (f32x4){0.f, 0.f, 0.f, 0.f};
            #pragma unroll
            for (int nt = 0; nt < 4; ++nt)
                #pragma unroll
                for (int r = 0; r < 4; ++r)
                    s[r] += lrelu(acc2[nt][r] + bb2[r]);
            #pragma unroll
            for (int r = 0; r < 4; ++r) {
                float t = s[r];
                t += __shfl_xor(t, 1); t += __shfl_xor(t, 2);
                t += __shfl_xor(t, 4); t += __shfl_xor(t, 8);
                s[r] = t;
            }
            if (l15 == 0) *(f32x4*)&aggrow[ii * 96 + wid * 16 + lg * 4] = s;
        }
        __syncthreads();
    }
    #undef BUILD
}

// ---- node MLP (unchanged from R1) ----
__global__ __launch_bounds__(256, 2)
void node_kernel(const float* __restrict__ x, const float* __restrict__ agg,
                 const short* __restrict__ Wn0T, const short* __restrict__ Wn1T,
                 const float* __restrict__ bn0, const float* __restrict__ bn1,
                 float* __restrict__ out)
{
    __shared__ short A2[64 * 168];
    __shared__ short H[64 * 264];
    const int tid = threadIdx.x;
    const int lane = tid & 63, wid = tid >> 6;
    const int l15 = lane & 15, lg = lane >> 4;
    const int r0 = blockIdx.x * 64;

    for (int t = tid; t < 64 * 160; t += 256) {
        int j = t / 160, c = t - j * 160;
        float vv = (c < 96) ? agg[(r0 + j) * 96 + c] : x[(r0 + j) * 64 + (c - 96)];
        A2[j * 168 + c] = f2bf(vv);
    }
    __syncthreads();

    {
        f32x4 acc[4][4];
        #pragma unroll
        for (int mt = 0; mt < 4; ++mt)
            #pragma unroll
            for (int nt = 0; nt < 4; ++nt) acc[mt][nt] = (f32x4){0.f, 0.f, 0.f, 0.f};
        const int n0 = wid * 64;
        #pragma unroll
        for (int ks = 0; ks < 5; ++ks) {
            const int k0 = ks * 32 + lg * 8;
            short8 a[4], bf[4];
            #pragma unroll
            for (int mt = 0; mt < 4; ++mt)
                a[mt] = *reinterpret_cast<const short8*>(&A2[(mt * 16 + l15) * 168 + k0]);
            #pragma unroll
            for (int nt = 0; nt < 4; ++nt)
                bf[nt] = *reinterpret_cast<const short8*>(&Wn0T[(n0 + nt * 16 + l15) * 160 + k0]);
            #pragma unroll
            for (int mt = 0; mt < 4; ++mt)
                #pragma unroll
                for (int nt = 0; nt < 4; ++nt)
                    acc[mt][nt] = __builtin_amdgcn_mfma_f32_16x16x32_bf16(a[mt], bf[nt], acc[mt][nt], 0, 0, 0);
        }
        #pragma unroll
        for (int nt = 0; nt < 4; ++nt) {
            const int col = n0 + nt * 16 + l15;
            const float bv = bn0[col];
            #pragma unroll
            for (int mt = 0; mt < 4; ++mt)
                #pragma unroll
                for (int r = 0; r < 4; ++r)
                    H[(mt * 16 + lg * 4 + r) * 264 + col] = f2bf(lrelu(acc[mt][nt][r] + bv));
        }
    }
    __syncthreads();

    {
        f32x4 acc[4];
        #pragma unroll
        for (int mt = 0; mt < 4; ++mt) acc[mt] = (f32x4){0.f, 0.f, 0.f, 0.f};
        #pragma unroll
        for (int ks = 0; ks < 8; ++ks) {
            const int k0 = ks * 32 + lg * 8;
            short8 bf = *reinterpret_cast<const short8*>(&Wn1T[(wid * 16 + l15) * 256 + k0]);
            #pragma unroll
            for (int mt = 0; mt < 4; ++mt) {
                short8 a = *reinterpret_cast<const short8*>(&H[(mt * 16 + l15) * 264 + k0]);
                acc[mt] = __builtin_amdgcn_mfma_f32_16x16x32_bf16(a, bf, acc[mt], 0, 0, 0);
            }
        }
        const int col = wid * 16 + l15;
        const float bv = bn1[col];
        #pragma unroll
        for (int mt = 0; mt < 4; ++mt)
            #pragma unroll
            for (int r = 0; r < 4; ++r)
                out[(r0 + mt * 16 + lg * 4 + r) * 64 + col] = acc[mt][r] + bv;
    }
}

extern "C" void kernel_launch(void* const* d_in, const int* in_sizes, int n_in,
                              void* d_out, int out_size, void* d_ws, size_t ws_size,
                              hipStream_t stream) {
    (void)in_sizes; (void)n_in; (void)out_size; (void)ws_size;
    const float* x    = (const float*)d_in[0];
    const float* feW0 = (const float*)d_in[1];
    const float* feb0 = (const float*)d_in[2];
    const float* feW1 = (const float*)d_in[3];
    const float* feb1 = (const float*)d_in[4];
    const float* feW2 = (const float*)d_in[5];
    const float* feb2 = (const float*)d_in[6];
    const float* fnW0 = (const float*)d_in[7];
    const float* fnb0 = (const float*)d_in[8];
    const float* fnW1 = (const float*)d_in[9];
    const float* fnb1 = (const float*)d_in[10];

    char* ws = (char*)d_ws;
    short* W1F   = (short*)(ws + 0);          // 131072
    short* W2F   = (short*)(ws + 131072);     // 65536
    short* W0uvF = (short*)(ws + 196608);     // 65536
    short* Wn0T  = (short*)(ws + 262144);     // 81920
    short* Wn1T  = (short*)(ws + 344064);     // 32768
    float* agg   = (float*)(ws + 376832);     // 3145728
    float* u     = (float*)(ws + 3522560);    // 8388608
    float* v     = (float*)(ws + 11911168);   // 8388608

    hipLaunchKernelGGL(prep_kernel, dim3(64), dim3(256), 0, stream,
                       feW0, feW1, feW2, fnW0, fnW1, W1F, W2F, W0uvF, Wn0T, Wn1T);
    hipLaunchKernelGGL(uv_kernel, dim3(128), dim3(256), 0, stream,
                       x, W0uvF, u, v);
    hipLaunchKernelGGL(edge_kernel, dim3(512), dim3(512), 0, stream,
                       x, feW0, feb0, feb1, feb2, W1F, W2F, u, v, agg);
    hipLaunchKernelGGL(node_kernel, dim3(128), dim3(256), 0, stream,
                       x, agg, Wn0T, Wn1T, fnb0, fnb1, (float*)d_out);
}